// Round 12
// baseline (161.471 us; speedup 1.0000x reference)
//
#include <hip/hip_runtime.h>

// mean(|box5(x) - box5(y)|), box5 = 5x5 uniform, pad=4.
// box(x)-box(y) = box(x-y), separable.
//
// One WAVE owns a 512-wide strip of R=8 output rows, split into LEFT and
// RIGHT 256-col halves with 4 cols/lane. Round-12 change: PERFECT
// instruction-level coalescing — every global_load_dwordx4 is lane i ->
// base + 16*i (1 KB contiguous, 16 cache lines). All prior variants used
// 8 cols/lane (32 B lane stride): each load touched 32 distinct lines for
// 1 KB of data — a TA/L1 scatter tax paid on every load, the one thing
// never varied across the 57-75 us plateau (r1-r11).
// Topology otherwise = r8's best point: 3 fence-clustered 4-row chunks
// (16 loads each, address-ordered), compiler-managed waits, no LDS, no
// barriers, XCD-swizzled grid. Seam: right-half lane 0 gets its halo from
// left-half lane 63 via one broadcast shuffle.

#define IMG_W 512
#define IMG_H 512
#define OUT_W 516
#define OUT_H 516
#define R     8                  // output rows per wave strip
#define SPI   65                 // ceil(516/8)
#define NT    256
#define WAVES (NT / 64)
#define NSTRIPS (64 * SPI)       // 4160 waves
#define NBLK  (NSTRIPS / WAVES)  // 1040 blocks (130 per XCD)
#define NPART 64

typedef float v4f __attribute__((ext_vector_type(4)));

__global__ __launch_bounds__(NT, 3) void box_loss_kernel(
    const float* __restrict__ x, const float* __restrict__ y,
    float* __restrict__ partial)
{
    const int t    = threadIdx.x;
    const int lane = t & 63;
    const int wid  = t >> 6;

    // bijective XCD swizzle: 1040 blocks -> 130 contiguous per XCD
    const int bid  = blockIdx.x;
    const int swz  = (bid & 7) * (NBLK / 8) + (bid >> 3);

    const int strip = swz * WAVES + wid;            // 0..4159
    const int b  = strip / SPI;                     // batch image
    const int s  = strip - b * SPI;                 // strip in image
    const int i0 = s * R;                           // first output row
    const int cL = 4 * lane;                        // left-half cols
    const int cR = 256 + 4 * lane;                  // right-half cols

    const float* xb = x + (size_t)b * (IMG_W * IMG_H);
    const float* yb = y + (size_t)b * (IMG_W * IMG_H);

    // rolling state: 5-row d-history + vertical sums, per half
    float ringL[5][4], ringR[5][4];
    float vL[4], vR[4];
    #pragma unroll
    for (int j = 0; j < 4; ++j) {
        vL[j] = 0.f; vR[j] = 0.f; ringL[4][j] = 0.f; ringR[4][j] = 0.f;
    }

    float acc = 0.f;

    // 3 chunks of 4 input rows (rows i0-4 .. i0+7).
    #pragma unroll
    for (int ch = 0; ch < 3; ++ch) {
        const int r0 = i0 - 4 + ch * 4;

        // chunk stage registers: 16 perfectly-coalesced 1KB loads,
        // address-ordered (x rows L,R then y rows L,R), fence-pinned.
        v4f xal[4], xar[4], yal[4], yar[4];
        __builtin_amdgcn_sched_barrier(0);
        #pragma unroll
        for (int mI = 0; mI < 4; ++mI) {
            const int rc = min(max(r0 + mI, 0), IMG_H - 1);
            const float* xr = xb + (size_t)rc * IMG_W;
            xal[mI] = *(const v4f*)(xr + cL);
            xar[mI] = *(const v4f*)(xr + cR);
        }
        #pragma unroll
        for (int mI = 0; mI < 4; ++mI) {
            const int rc = min(max(r0 + mI, 0), IMG_H - 1);
            const float* yr = yb + (size_t)rc * IMG_W;
            yal[mI] = *(const v4f*)(yr + cL);
            yar[mI] = *(const v4f*)(yr + cR);
        }
        __builtin_amdgcn_sched_barrier(0);

        #pragma unroll
        for (int mI = 0; mI < 4; ++mI) {
            const int k = ch * 4 + mI;      // 0..11 (compile-time)
            const int r = r0 + mI;          // input row consumed
            const float m = (r >= 0 && r < IMG_H) ? 1.f : 0.f;

            float dL[4], dR[4];
            dL[0] = (xal[mI].x - yal[mI].x) * m;
            dL[1] = (xal[mI].y - yal[mI].y) * m;
            dL[2] = (xal[mI].z - yal[mI].z) * m;
            dL[3] = (xal[mI].w - yal[mI].w) * m;
            dR[0] = (xar[mI].x - yar[mI].x) * m;
            dR[1] = (xar[mI].y - yar[mI].y) * m;
            dR[2] = (xar[mI].z - yar[mI].z) * m;
            dR[3] = (xar[mI].w - yar[mI].w) * m;

            if (k < 4) {
                #pragma unroll
                for (int j = 0; j < 4; ++j) {
                    ringL[k][j] = dL[j]; vL[j] += dL[j];
                    ringR[k][j] = dR[j]; vR[j] += dR[j];
                }
            } else {
                const int i = i0 + (k - 4);     // output row (wave-uniform)
                const int slot = k % 5;         // compile-time after unroll
                #pragma unroll
                for (int j = 0; j < 4; ++j) {
                    vL[j] += dL[j] - ringL[slot][j]; ringL[slot][j] = dL[j];
                    vR[j] += dR[j] - ringR[slot][j]; ringR[slot][j] = dR[j];
                }

                // halos: prev lane's 4 col-sums; right lane0 takes the
                // seam from left lane63 (broadcast shuffle)
                float hL[4], hR[4], bL[4];
                #pragma unroll
                for (int j = 0; j < 4; ++j) {
                    hL[j] = __shfl_up(vL[j], 1, 64);
                    hR[j] = __shfl_up(vR[j], 1, 64);
                    bL[j] = __shfl(vL[j], 63, 64);
                }
                if (lane == 0) {
                    #pragma unroll
                    for (int j = 0; j < 4; ++j) { hL[j] = 0.f; hR[j] = bL[j]; }
                }

                // left half: out cols 4*lane .. 4*lane+3
                const float l0 = hL[0]+hL[1]+hL[2]+hL[3]+vL[0];
                const float l1 = l0 - hL[0] + vL[1];
                const float l2 = l1 - hL[1] + vL[2];
                const float l3 = l2 - hL[2] + vL[3];
                // right half: out cols 256+4*lane .. +3
                const float r0s = hR[0]+hR[1]+hR[2]+hR[3]+vR[0];
                const float r1s = r0s - hR[0] + vR[1];
                const float r2s = r1s - hR[1] + vR[2];
                const float r3s = r2s - hR[2] + vR[3];

                const float rowmask = (i < OUT_H) ? 1.f : 0.f;
                acc += rowmask * (fabsf(l0) + fabsf(l1) + fabsf(l2) + fabsf(l3)
                                + fabsf(r0s) + fabsf(r1s) + fabsf(r2s) + fabsf(r3s));

                // right edge: out cols 512..515 (truncated windows),
                // from lane 63's right-half sums (cols 508..511)
                const float em = (lane == 63) ? rowmask : 0.f;
                const float e0 = vR[0] + vR[1] + vR[2] + vR[3];
                const float e1 = vR[1] + vR[2] + vR[3];
                const float e2 = vR[2] + vR[3];
                const float e3 = vR[3];
                acc += em * (fabsf(e0) + fabsf(e1) + fabsf(e2) + fabsf(e3));
            }
        }
    }

    // wave reduction, then one atomic per wave spread across 64 slots
    #pragma unroll
    for (int off = 32; off > 0; off >>= 1)
        acc += __shfl_down(acc, off, 64);
    if (lane == 0)
        atomicAdd(partial + (strip & (NPART - 1)), acc);
}

__global__ void finalize_kernel(const float* __restrict__ partial,
                                float* __restrict__ out)
{
    float s = 0.f;
    #pragma unroll
    for (int k = 0; k < NPART; ++k) s += partial[k];
    // each output scaled by 1/25 (uniform kernel), mean over 64*516*516
    out[0] = s * (1.0f / (25.0f * 64.0f * 516.0f * 516.0f));
}

extern "C" void kernel_launch(void* const* d_in, const int* in_sizes, int n_in,
                              void* d_out, int out_size, void* d_ws, size_t ws_size,
                              hipStream_t stream) {
    const float* x = (const float*)d_in[0];
    const float* y = (const float*)d_in[1];
    float* out = (float*)d_out;
    float* ws  = (float*)d_ws;

    hipMemsetAsync(ws, 0, NPART * sizeof(float), stream);

    dim3 grid(NBLK);   // 1040 blocks x 256 threads = 4160 waves
    box_loss_kernel<<<grid, NT, 0, stream>>>(x, y, ws);
    finalize_kernel<<<1, 1, 0, stream>>>(ws, out);
}

// Round 13
// 151.534 us; speedup vs baseline: 1.0656x; 1.0656x over previous
//
#include <hip/hip_runtime.h>

// mean(|box5(x) - box5(y)|), box5 = 5x5 uniform, pad=4.
// box(x)-box(y) = box(x-y), separable.
//
// One WAVE owns a 512-wide strip of R=9 output rows; lane owns 8 cols.
// Vertical 5-row rolling sum in registers (ring[5][8]); horizontal 5-tap
// via 4 x __shfl_up. No LDS, no barriers. Chunked fence-pinned load
// bursts (r8's best-measured structure, 57.2 us).
//
// Round-13 change: R=8 -> R=9 (HBM CHANNEL-PHASE DECORRELATION).
// All 13 prior variants used 16 KB-aligned strip bases: in 256 B channel
// units that is 64*s mod ~128 -> only TWO distinct start phases, so every
// resident wave's burst front marches the channel space in lockstep
// (half the channels idle, rest ~40x oversubscribed -> the invariant
// 1.7 TB/s cap). R=9 -> strip base 18 KB = 72 ch-units, gcd(72,128)=8
// -> 16 distinct phases, ~even instantaneous channel coverage.
// Amplification ~unchanged (13/9 vs 12/8). Everything else = r8.

#define IMG_W 512
#define IMG_H 512
#define OUT_W 516
#define OUT_H 516
#define R     9                  // output rows per wave strip (PHASE LEVER)
#define SPI   58                 // ceil(516/9)
#define NT    256
#define WAVES (NT / 64)
#define NSTRIPS (64 * SPI)       // 3712 waves
#define NBLK  (NSTRIPS / WAVES)  // 928 blocks (116 per XCD, bijective)
#define NPART 64
#define NROWS 13                 // input rows per strip (R + 4)

typedef float v4f __attribute__((ext_vector_type(4)));

// Load chunk rows [base, base+nr) (strip-relative) of x then y as
// address-ordered bursts, fence-pinned into one issue cluster.
#define LOADCHUNK(base, nr)                                               \
    __builtin_amdgcn_sched_barrier(0);                                    \
    _Pragma("unroll")                                                     \
    for (int q = 0; q < (nr); ++q) {                                      \
        const int rc = min(max(i0 - 4 + (base) + q, 0), IMG_H - 1);       \
        const float* xr = xb + (size_t)rc * IMG_W;                        \
        xa[q] = *(const v4f*)(xr); xc[q] = *(const v4f*)(xr + 4);         \
    }                                                                     \
    _Pragma("unroll")                                                     \
    for (int q = 0; q < (nr); ++q) {                                      \
        const int rc = min(max(i0 - 4 + (base) + q, 0), IMG_H - 1);       \
        const float* yr = yb + (size_t)rc * IMG_W;                        \
        ya[q] = *(const v4f*)(yr); yc[q] = *(const v4f*)(yr + 4);         \
    }                                                                     \
    __builtin_amdgcn_sched_barrier(0);

__global__ __launch_bounds__(NT, 2) void box_loss_kernel(
    const float* __restrict__ x, const float* __restrict__ y,
    float* __restrict__ partial)
{
    const int t    = threadIdx.x;
    const int lane = t & 63;
    const int wid  = t >> 6;

    // bijective XCD swizzle: 928 blocks -> 116 contiguous per XCD
    const int bid  = blockIdx.x;
    const int swz  = (bid & 7) * (NBLK / 8) + (bid >> 3);

    const int strip = swz * WAVES + wid;            // 0..3711
    const int b  = strip / SPI;                     // batch image
    const int s  = strip - b * SPI;                 // strip in image
    const int i0 = s * R;                           // first output row
    const int c0 = lane * 8;                        // this lane's 8 columns

    const float* xb = x + (size_t)b * (IMG_W * IMG_H) + c0;
    const float* yb = y + (size_t)b * (IMG_W * IMG_H) + c0;

    // chunk stage registers (max chunk = 5 rows = 20 loads)
    v4f xa[5], xc[5], ya[5], yc[5];

    // d-row history ring + vertical rolling sums, all in registers.
    float ring[5][8];
    float v[8];
    #pragma unroll
    for (int j = 0; j < 8; ++j) { v[j] = 0.f; ring[4][j] = 0.f; }

    float acc = 0.f;

    // 13 input rows in chunks {4,4,5}: k=0..3 warm-up (rows i0-4..i0-1),
    // k=4..12 -> output rows i0..i0+8.
    #pragma unroll
    for (int k = 0; k < NROWS; ++k) {
        if (k == 0) { LOADCHUNK(0, 4); }
        if (k == 4) { LOADCHUNK(4, 4); }
        if (k == 8) { LOADCHUNK(8, 5); }
        const int mI = (k < 4) ? k : (k < 8) ? (k - 4) : (k - 8); // const
        const int r = i0 - 4 + k;           // input row consumed this step
        const float m = (r >= 0 && r < IMG_H) ? 1.f : 0.f;

        float d[8];
        d[0] = (xa[mI].x - ya[mI].x) * m; d[1] = (xa[mI].y - ya[mI].y) * m;
        d[2] = (xa[mI].z - ya[mI].z) * m; d[3] = (xa[mI].w - ya[mI].w) * m;
        d[4] = (xc[mI].x - yc[mI].x) * m; d[5] = (xc[mI].y - yc[mI].y) * m;
        d[6] = (xc[mI].z - yc[mI].z) * m; d[7] = (xc[mI].w - yc[mI].w) * m;

        if (k < 4) {
            // warm-up: stash into ring slots 0..3, accumulate v
            #pragma unroll
            for (int j = 0; j < 8; ++j) { ring[k][j] = d[j]; v[j] += d[j]; }
        } else {
            const int i = i0 + (k - 4);     // output row (wave-uniform)
            const int slot = k % 5;         // compile-time after unroll
            #pragma unroll
            for (int j = 0; j < 8; ++j) {
                v[j] += d[j] - ring[slot][j];
                ring[slot][j] = d[j];
            }

            // halo: previous lane's v[4..7] = vsums for cols c0-4..c0-1
            float h0 = __shfl_up(v[4], 1, 64);
            float h1 = __shfl_up(v[5], 1, 64);
            float h2 = __shfl_up(v[6], 1, 64);
            float h3 = __shfl_up(v[7], 1, 64);
            if (lane == 0) { h0 = 0.f; h1 = 0.f; h2 = 0.f; h3 = 0.f; }

            // sliding horizontal 5-tap over {h0..h3, v0..v7}
            const float s0 = h0 + h1 + h2 + h3 + v[0];
            const float s1 = s0 + v[1] - h0;
            const float s2 = s1 + v[2] - h1;
            const float s3 = s2 + v[3] - h2;
            const float s4 = s3 + v[4] - h3;
            const float s5 = s4 + v[5] - v[0];
            const float s6 = s5 + v[6] - v[1];
            const float s7 = s6 + v[7] - v[2];

            const float rowmask = (i < OUT_H) ? 1.f : 0.f; // ragged strip
            acc += rowmask * (fabsf(s0) + fabsf(s1) + fabsf(s2) + fabsf(s3)
                            + fabsf(s4) + fabsf(s5) + fabsf(s6) + fabsf(s7));

            // right edge: output cols 512..515 (truncated windows)
            const float em = (lane == 63) ? rowmask : 0.f;
            const float e0 = v[4] + v[5] + v[6] + v[7];
            const float e1 = v[5] + v[6] + v[7];
            const float e2 = v[6] + v[7];
            const float e3 = v[7];
            acc += em * (fabsf(e0) + fabsf(e1) + fabsf(e2) + fabsf(e3));
        }
    }

    // wave reduction, then one atomic per wave spread across 64 slots
    #pragma unroll
    for (int off = 32; off > 0; off >>= 1)
        acc += __shfl_down(acc, off, 64);
    if (lane == 0)
        atomicAdd(partial + (strip & (NPART - 1)), acc);
}

__global__ void finalize_kernel(const float* __restrict__ partial,
                                float* __restrict__ out)
{
    float s = 0.f;
    #pragma unroll
    for (int k = 0; k < NPART; ++k) s += partial[k];
    // each output scaled by 1/25 (uniform kernel), mean over 64*516*516
    out[0] = s * (1.0f / (25.0f * 64.0f * 516.0f * 516.0f));
}

extern "C" void kernel_launch(void* const* d_in, const int* in_sizes, int n_in,
                              void* d_out, int out_size, void* d_ws, size_t ws_size,
                              hipStream_t stream) {
    const float* x = (const float*)d_in[0];
    const float* y = (const float*)d_in[1];
    float* out = (float*)d_out;
    float* ws  = (float*)d_ws;

    hipMemsetAsync(ws, 0, NPART * sizeof(float), stream);

    dim3 grid(NBLK);   // 928 blocks x 256 threads = 3712 waves
    box_loss_kernel<<<grid, NT, 0, stream>>>(x, y, ws);
    finalize_kernel<<<1, 1, 0, stream>>>(ws, out);
}

// Round 14
// 149.059 us; speedup vs baseline: 1.0833x; 1.0166x over previous
//
#include <hip/hip_runtime.h>

// mean(|box5(x) - box5(y)|), box5 = 5x5 uniform, pad=4.
// box(x)-box(y) = box(x-y), separable.
//
// One WAVE owns a 512-wide strip of R=17 output rows; lane owns 8 cols.
// Vertical 5-row rolling sum in registers (ring[5][8]); horizontal 5-tap
// via 4 x __shfl_up. No LDS, no barriers. Fence-pinned 4-row load chunks
// (proven size; r11 showed 6-row chunks collapse in regalloc).
//
// Round-14: R=9 -> R=17. Two goals:
//  (1) TRAFFIC: re-read amplification (R+4)/R: 1.44 -> 1.24, logical
//      198 -> 170 MB. If the system is service-rate-bound (~1.9 TB/s),
//      duration tracks FETCH -> ~45 us.
//  (2) Keep the phase win: R odd => strip base = 8R channel-units,
//      gcd(8R,128)=8 => all 16 possible phases (r13's +13%). Phase lever
//      is saturated at 16 (row granularity is 8 units); traffic is the
//      remaining lever this round isolates.
// Discriminator: stalls/wave rises 3->5. If duration goes FLAT or worse
// despite -14% traffic, the per-wave stall chain governs (r11's hint) and
// the next move is stall overlap, not traffic.

#define IMG_W 512
#define IMG_H 512
#define OUT_W 516
#define OUT_H 516
#define R     17                 // output rows per wave strip (odd!)
#define SPI   31                 // ceil(516/17)
#define NT    256
#define WAVES (NT / 64)
#define NSTRIPS (64 * SPI)       // 1984 waves
#define NBLK  (NSTRIPS / WAVES)  // 496 blocks (62 per XCD, bijective)
#define NPART 64
#define NROWS 21                 // input rows per strip (R + 4)

typedef float v4f __attribute__((ext_vector_type(4)));

// Load chunk rows [base, base+nr) (strip-relative) of x then y as
// address-ordered bursts, fence-pinned into one issue cluster.
#define LOADCHUNK(base, nr)                                               \
    __builtin_amdgcn_sched_barrier(0);                                    \
    _Pragma("unroll")                                                     \
    for (int q = 0; q < (nr); ++q) {                                      \
        const int rc = min(max(i0 - 4 + (base) + q, 0), IMG_H - 1);       \
        const float* xr = xb + (size_t)rc * IMG_W;                        \
        xa[q] = *(const v4f*)(xr); xc[q] = *(const v4f*)(xr + 4);         \
    }                                                                     \
    _Pragma("unroll")                                                     \
    for (int q = 0; q < (nr); ++q) {                                      \
        const int rc = min(max(i0 - 4 + (base) + q, 0), IMG_H - 1);       \
        const float* yr = yb + (size_t)rc * IMG_W;                        \
        ya[q] = *(const v4f*)(yr); yc[q] = *(const v4f*)(yr + 4);         \
    }                                                                     \
    __builtin_amdgcn_sched_barrier(0);

__global__ __launch_bounds__(NT, 2) void box_loss_kernel(
    const float* __restrict__ x, const float* __restrict__ y,
    float* __restrict__ partial)
{
    const int t    = threadIdx.x;
    const int lane = t & 63;
    const int wid  = t >> 6;

    // bijective XCD swizzle: 496 blocks -> 62 contiguous per XCD
    const int bid  = blockIdx.x;
    const int swz  = (bid & 7) * (NBLK / 8) + (bid >> 3);

    const int strip = swz * WAVES + wid;            // 0..1983
    const int b  = strip / SPI;                     // batch image
    const int s  = strip - b * SPI;                 // strip in image
    const int i0 = s * R;                           // first output row
    const int c0 = lane * 8;                        // this lane's 8 columns

    const float* xb = x + (size_t)b * (IMG_W * IMG_H) + c0;
    const float* yb = y + (size_t)b * (IMG_W * IMG_H) + c0;

    // chunk stage registers (max chunk = 5 rows = 20 loads)
    v4f xa[5], xc[5], ya[5], yc[5];

    // d-row history ring + vertical rolling sums, all in registers.
    float ring[5][8];
    float v[8];
    #pragma unroll
    for (int j = 0; j < 8; ++j) { v[j] = 0.f; ring[4][j] = 0.f; }

    float acc = 0.f;

    // 21 input rows in chunks {4,4,4,4,5}: k=0..3 warm-up
    // (rows i0-4..i0-1), k=4..20 -> output rows i0..i0+16.
    #pragma unroll
    for (int k = 0; k < NROWS; ++k) {
        if (k == 0)  { LOADCHUNK(0, 4);  }
        if (k == 4)  { LOADCHUNK(4, 4);  }
        if (k == 8)  { LOADCHUNK(8, 4);  }
        if (k == 12) { LOADCHUNK(12, 4); }
        if (k == 16) { LOADCHUNK(16, 5); }
        const int mI = (k < 4) ? k : (k < 8) ? (k - 4) : (k < 12) ? (k - 8)
                     : (k < 16) ? (k - 12) : (k - 16);   // compile-time
        const int r = i0 - 4 + k;           // input row consumed this step
        const float m = (r >= 0 && r < IMG_H) ? 1.f : 0.f;

        float d[8];
        d[0] = (xa[mI].x - ya[mI].x) * m; d[1] = (xa[mI].y - ya[mI].y) * m;
        d[2] = (xa[mI].z - ya[mI].z) * m; d[3] = (xa[mI].w - ya[mI].w) * m;
        d[4] = (xc[mI].x - yc[mI].x) * m; d[5] = (xc[mI].y - yc[mI].y) * m;
        d[6] = (xc[mI].z - yc[mI].z) * m; d[7] = (xc[mI].w - yc[mI].w) * m;

        if (k < 4) {
            // warm-up: stash into ring slots 0..3, accumulate v
            #pragma unroll
            for (int j = 0; j < 8; ++j) { ring[k][j] = d[j]; v[j] += d[j]; }
        } else {
            const int i = i0 + (k - 4);     // output row (wave-uniform)
            const int slot = k % 5;         // compile-time after unroll
            #pragma unroll
            for (int j = 0; j < 8; ++j) {
                v[j] += d[j] - ring[slot][j];
                ring[slot][j] = d[j];
            }

            // halo: previous lane's v[4..7] = vsums for cols c0-4..c0-1
            float h0 = __shfl_up(v[4], 1, 64);
            float h1 = __shfl_up(v[5], 1, 64);
            float h2 = __shfl_up(v[6], 1, 64);
            float h3 = __shfl_up(v[7], 1, 64);
            if (lane == 0) { h0 = 0.f; h1 = 0.f; h2 = 0.f; h3 = 0.f; }

            // sliding horizontal 5-tap over {h0..h3, v0..v7}
            const float s0 = h0 + h1 + h2 + h3 + v[0];
            const float s1 = s0 + v[1] - h0;
            const float s2 = s1 + v[2] - h1;
            const float s3 = s2 + v[3] - h2;
            const float s4 = s3 + v[4] - h3;
            const float s5 = s4 + v[5] - v[0];
            const float s6 = s5 + v[6] - v[1];
            const float s7 = s6 + v[7] - v[2];

            const float rowmask = (i < OUT_H) ? 1.f : 0.f; // ragged strip
            acc += rowmask * (fabsf(s0) + fabsf(s1) + fabsf(s2) + fabsf(s3)
                            + fabsf(s4) + fabsf(s5) + fabsf(s6) + fabsf(s7));

            // right edge: output cols 512..515 (truncated windows)
            const float em = (lane == 63) ? rowmask : 0.f;
            const float e0 = v[4] + v[5] + v[6] + v[7];
            const float e1 = v[5] + v[6] + v[7];
            const float e2 = v[6] + v[7];
            const float e3 = v[7];
            acc += em * (fabsf(e0) + fabsf(e1) + fabsf(e2) + fabsf(e3));
        }
    }

    // wave reduction, then one atomic per wave spread across 64 slots
    #pragma unroll
    for (int off = 32; off > 0; off >>= 1)
        acc += __shfl_down(acc, off, 64);
    if (lane == 0)
        atomicAdd(partial + (strip & (NPART - 1)), acc);
}

__global__ void finalize_kernel(const float* __restrict__ partial,
                                float* __restrict__ out)
{
    float s = 0.f;
    #pragma unroll
    for (int k = 0; k < NPART; ++k) s += partial[k];
    // each output scaled by 1/25 (uniform kernel), mean over 64*516*516
    out[0] = s * (1.0f / (25.0f * 64.0f * 516.0f * 516.0f));
}

extern "C" void kernel_launch(void* const* d_in, const int* in_sizes, int n_in,
                              void* d_out, int out_size, void* d_ws, size_t ws_size,
                              hipStream_t stream) {
    const float* x = (const float*)d_in[0];
    const float* y = (const float*)d_in[1];
    float* out = (float*)d_out;
    float* ws  = (float*)d_ws;

    hipMemsetAsync(ws, 0, NPART * sizeof(float), stream);

    dim3 grid(NBLK);   // 496 blocks x 256 threads = 1984 waves
    box_loss_kernel<<<grid, NT, 0, stream>>>(x, y, ws);
    finalize_kernel<<<1, 1, 0, stream>>>(ws, out);
}